// Round 4
// baseline (345.026 us; speedup 1.0000x reference)
//
#include <hip/hip_runtime.h>
#include <hip/hip_bf16.h>

typedef __attribute__((ext_vector_type(4))) float f32x4;
typedef __attribute__((ext_vector_type(8))) short bf16x8;

#define BM 128
#define BN 128
#define BK 32
#define KDIM 512
#define NT (KDIM / BK)   // 16 K-tiles

// fp32 -> packed 2x bf16 (RNE). Compiler emits v_cvt_pk_bf16_f32.
__device__ __forceinline__ unsigned int bfpack(float a, float b) {
  __hip_bfloat162 h = __float22bfloat162_rn(float2{a, b});
  union { __hip_bfloat162 h2; unsigned int u; } c;
  c.h2 = h;
  return c.u;
}

// 16B-granule XOR swizzle (verified conflict-free in R3: SQ_LDS_BANK_CONFLICT=0).
__device__ __forceinline__ int swz(int row, int col) {
  return col ^ (((row >> 1) & 3) << 3);
}

// T4 barrier: order LDS only (lgkmcnt), let global loads stay in flight.
// __syncthreads() would emit s_waitcnt vmcnt(0) and drain the prefetch.
__device__ __forceinline__ void lds_barrier() {
  __builtin_amdgcn_sched_barrier(0);
  asm volatile("s_waitcnt lgkmcnt(0)" ::: "memory");
  __builtin_amdgcn_s_barrier();
  __builtin_amdgcn_sched_barrier(0);
}

__launch_bounds__(256, 4)
__global__ void moe_grouped_gemm(const float* __restrict__ A,
                                 const float* __restrict__ W,
                                 float* __restrict__ C) {
  // bf16 tiles, double buffered: 2*(128*32 + 128*32)*2B = 32 KiB LDS.
  __shared__ ushort As[2][BM][BK];
  __shared__ ushort Bs[2][BN][BK];

  const int tid  = threadIdx.x;
  const int lane = tid & 63;
  const int wid  = tid >> 6;     // 4 waves
  const int wm   = wid >> 1;     // 0..1  (64-row half)
  const int wn   = wid & 1;      // 0..1  (64-col half)

  // XCD-aware remap: each XCD owns one expert; n fastest => 4 consecutive
  // blocks share one A-panel (L2 reuse).
  const int b = blockIdx.x;
  const int L = (b & 7) * 1024 + (b >> 3);
  const int e  = L >> 10;        // expert
  const int t  = L & 1023;
  const int mt = t >> 2;         // 256 m-tiles
  const int nt = t & 3;          // 4 n-tiles

  const size_t mBase = (size_t)e * 32768 + (size_t)mt * BM;
  const int    nBase = nt * BN;

  const float* Ap = A + mBase * KDIM;
  const float* Wp = W + ((size_t)e * 512 + nBase) * KDIM;

  // staging geometry: 128x32 floats / 256 threads = 4 float4 per thread
  const int srow = tid >> 3;            // 8 threads per row
  const int scol = (tid & 7) << 2;      // 4 floats each

  f32x4 acc[4][4];
  #pragma unroll
  for (int i = 0; i < 4; ++i)
    #pragma unroll
    for (int j = 0; j < 4; ++j)
      acc[i][j] = (f32x4){0.f, 0.f, 0.f, 0.f};

  float4 ra[4], rb[4];

  // ---- prologue: tile 0 -> LDS[0]; issue tile 1 loads ----
  #pragma unroll
  for (int i = 0; i < 4; ++i) {
    const int row = srow + i * 32;
    ra[i] = *(const float4*)(Ap + row * KDIM + scol);
    rb[i] = *(const float4*)(Wp + row * KDIM + scol);
  }
  #pragma unroll
  for (int i = 0; i < 4; ++i) {
    const int row = srow + i * 32;
    const int sc  = swz(row, scol);
    uint2 pa, pb;
    pa.x = bfpack(ra[i].x, ra[i].y); pa.y = bfpack(ra[i].z, ra[i].w);
    pb.x = bfpack(rb[i].x, rb[i].y); pb.y = bfpack(rb[i].z, rb[i].w);
    *(uint2*)&As[0][row][sc] = pa;
    *(uint2*)&Bs[0][row][sc] = pb;
  }
  #pragma unroll
  for (int i = 0; i < 4; ++i) {
    const int row = srow + i * 32;
    ra[i] = *(const float4*)(Ap + row * KDIM + BK + scol);
    rb[i] = *(const float4*)(Wp + row * KDIM + BK + scol);
  }

  // Main loop: ONE lgkm-only barrier per iter; vmcnt never drained in-loop.
  //   C(k) reads LDS[k&1]      <- written by W(k-1), separated by barrier(k)
  //   W(k) writes LDS[(k+1)&1] <- last read by C(k-1); C's reads completed
  //                               (compiler lgkm waits before MFMA) before
  //                               that wave crossed barrier(k).
  for (int kt = 0; kt < NT; ++kt) {
    lds_barrier();

    // ---- phase W: cvt + write tile kt+1 into the other buffer ----
    // (counted vmcnt waits for last iter's loads appear here, not at barrier)
    if (kt + 1 < NT) {
      const int nb = (kt + 1) & 1;
      #pragma unroll
      for (int i = 0; i < 4; ++i) {
        const int row = srow + i * 32;
        const int sc  = swz(row, scol);
        uint2 pa, pb;
        pa.x = bfpack(ra[i].x, ra[i].y); pa.y = bfpack(ra[i].z, ra[i].w);
        pb.x = bfpack(rb[i].x, rb[i].y); pb.y = bfpack(rb[i].z, rb[i].w);
        *(uint2*)&As[nb][row][sc] = pa;
        *(uint2*)&Bs[nb][row][sc] = pb;
      }
    }

    // ---- phase I: issue tile kt+2 global loads (fly across next barrier) ----
    if (kt + 2 < NT) {
      const int k0 = (kt + 2) * BK;
      #pragma unroll
      for (int i = 0; i < 4; ++i) {
        const int row = srow + i * 32;
        ra[i] = *(const float4*)(Ap + row * KDIM + k0 + scol);
        rb[i] = *(const float4*)(Wp + row * KDIM + k0 + scol);
      }
    }
    __builtin_amdgcn_sched_barrier(0);

    // ---- phase C: compute current tile from LDS[kt&1] ----
    {
      const int buf = kt & 1;
      bf16x8 bf[4], af[4];
      #pragma unroll
      for (int ni = 0; ni < 4; ++ni) {
        const int rrow = wn * 64 + ni * 16 + (lane & 15);
        const int kc   = swz(rrow, (lane >> 4) << 3);
        bf[ni] = *(const bf16x8*)&Bs[buf][rrow][kc];
      }
      #pragma unroll
      for (int mi = 0; mi < 4; ++mi) {
        const int arow = wm * 64 + mi * 16 + (lane & 15);
        const int kc   = swz(arow, (lane >> 4) << 3);
        af[mi] = *(const bf16x8*)&As[buf][arow][kc];
      }
      #pragma unroll
      for (int mi = 0; mi < 4; ++mi)
        #pragma unroll
        for (int ni = 0; ni < 4; ++ni)
          acc[mi][ni] = __builtin_amdgcn_mfma_f32_16x16x32_bf16(af[mi], bf[ni], acc[mi][ni], 0, 0, 0);
    }
  }

  // ---- epilogue: C[m][n], row = (lane>>4)*4 + reg, col = lane&15 ----
  #pragma unroll
  for (int mi = 0; mi < 4; ++mi) {
    #pragma unroll
    for (int reg = 0; reg < 4; ++reg) {
      const int r = wm * 64 + mi * 16 + ((lane >> 4) << 2) + reg;
      float* rowp = C + (mBase + r) * 512 + nBase + wn * 64 + (lane & 15);
      #pragma unroll
      for (int ni = 0; ni < 4; ++ni)
        __builtin_nontemporal_store(acc[mi][ni][reg], rowp + ni * 16);
    }
  }
}

extern "C" void kernel_launch(void* const* d_in, const int* in_sizes, int n_in,
                              void* d_out, int out_size, void* d_ws, size_t ws_size,
                              hipStream_t stream) {
  const float* inputs = (const float*)d_in[0];   // [262144, 512] fp32
  const float* weight = (const float*)d_in[1];   // [8, 512, 512] fp32
  float* out = (float*)d_out;                    // [262144, 512] fp32
  (void)d_ws; (void)ws_size; (void)in_sizes; (void)n_in;

  moe_grouped_gemm<<<8192, 256, 0, stream>>>(inputs, weight, out);
}

// Round 5
// 324.001 us; speedup vs baseline: 1.0649x; 1.0649x over previous
//
#include <hip/hip_runtime.h>
#include <hip/hip_bf16.h>

typedef __attribute__((ext_vector_type(4))) float f32x4;
typedef __attribute__((ext_vector_type(8))) short bf16x8;

#define BM 256
#define BN 256
#define BK 32
#define KDIM 512
#define NT (KDIM / BK)   // 16 K-tiles

// fp32 -> packed 2x bf16 (RNE). Compiler emits v_cvt_pk_bf16_f32.
__device__ __forceinline__ unsigned int bfpack(float a, float b) {
  __hip_bfloat162 h = __float22bfloat162_rn(float2{a, b});
  union { __hip_bfloat162 h2; unsigned int u; } c;
  c.h2 = h;
  return c.u;
}

// 16B-granule XOR swizzle (verified conflict-free in R3/R4: SQ_LDS_BANK_CONFLICT=0).
__device__ __forceinline__ int swz(int row, int col) {
  return col ^ (((row >> 1) & 3) << 3);
}

__launch_bounds__(512, 2)
__global__ void moe_grouped_gemm(const float* __restrict__ A,
                                 const float* __restrict__ W,
                                 float* __restrict__ C) {
  // bf16 tiles, double buffered: 2*(256*32 + 256*32)*2B = 64 KiB LDS.
  // 256x256 tile doubles FLOP per staged byte (the R2-R4 invariant bound)
  // and halves L2 read traffic (A re-read 2x instead of 4x).
  __shared__ ushort As[2][BM][BK];
  __shared__ ushort Bs[2][BN][BK];

  const int tid  = threadIdx.x;
  const int lane = tid & 63;
  const int wid  = tid >> 6;     // 8 waves
  const int wm   = wid >> 2;     // 0..1  (128-row half)
  const int wn   = wid & 3;      // 0..3  (64-col strip)

  // XCD mapping: 2048 blocks; b&7 = XCD = expert. b>>3 enumerates the
  // expert's 128 m-tiles x 2 n-tiles, n fastest => consecutive blocks share
  // one 512 KB A-panel; expert's full 1 MB weight stays L2-resident.
  const int b  = blockIdx.x;
  const int e  = b & 7;
  const int t  = b >> 3;         // 0..255
  const int mt = t >> 1;         // 128 m-tiles
  const int nt = t & 1;          // 2 n-tiles

  const size_t mBase = (size_t)e * 32768 + (size_t)mt * BM;
  const int    nBase = nt * BN;

  const float* Ap = A + mBase * KDIM;
  const float* Wp = W + ((size_t)e * 512 + nBase) * KDIM;

  // staging geometry: 256x32 floats / 512 threads = 4 float4 per thread/matrix
  const int srow = tid >> 3;            // 0..63, 8 threads per row
  const int scol = (tid & 7) << 2;      // 4 floats each

  f32x4 acc[8][4];
  #pragma unroll
  for (int i = 0; i < 8; ++i)
    #pragma unroll
    for (int j = 0; j < 4; ++j)
      acc[i][j] = (f32x4){0.f, 0.f, 0.f, 0.f};

  float4 ra[4], rb[4];

  // ---- prologue: tile 0 -> LDS[0]; issue tile 1 loads ----
  #pragma unroll
  for (int i = 0; i < 4; ++i) {
    const int row = srow + i * 64;
    ra[i] = *(const float4*)(Ap + row * KDIM + scol);
    rb[i] = *(const float4*)(Wp + row * KDIM + scol);
  }
  #pragma unroll
  for (int i = 0; i < 4; ++i) {
    const int row = srow + i * 64;
    const int sc  = swz(row, scol);
    uint2 pa, pb;
    pa.x = bfpack(ra[i].x, ra[i].y); pa.y = bfpack(ra[i].z, ra[i].w);
    pb.x = bfpack(rb[i].x, rb[i].y); pb.y = bfpack(rb[i].z, rb[i].w);
    *(uint2*)&As[0][row][sc] = pa;
    *(uint2*)&Bs[0][row][sc] = pb;
  }
  #pragma unroll
  for (int i = 0; i < 4; ++i) {
    const int row = srow + i * 64;
    ra[i] = *(const float4*)(Ap + row * KDIM + BK + scol);
    rb[i] = *(const float4*)(Wp + row * KDIM + BK + scol);
  }

  // Main loop: one barrier per iter.
  //   C(k) reads LDS[k&1]      <- written by W(k-1), separated by sync(k)
  //   W(k) writes LDS[(k+1)&1] <- last read by C(k-1), separated by sync(k)
  for (int kt = 0; kt < NT; ++kt) {
    __syncthreads();

    // ---- phase W: cvt + write tile kt+1 into the other buffer ----
    if (kt + 1 < NT) {
      const int nb = (kt + 1) & 1;
      #pragma unroll
      for (int i = 0; i < 4; ++i) {
        const int row = srow + i * 64;
        const int sc  = swz(row, scol);
        uint2 pa, pb;
        pa.x = bfpack(ra[i].x, ra[i].y); pa.y = bfpack(ra[i].z, ra[i].w);
        pb.x = bfpack(rb[i].x, rb[i].y); pb.y = bfpack(rb[i].z, rb[i].w);
        *(uint2*)&As[nb][row][sc] = pa;
        *(uint2*)&Bs[nb][row][sc] = pb;
      }
    }
    __builtin_amdgcn_sched_barrier(0);

    // ---- phase I: issue tile kt+2 global loads ----
    if (kt + 2 < NT) {
      const int k0 = (kt + 2) * BK;
      #pragma unroll
      for (int i = 0; i < 4; ++i) {
        const int row = srow + i * 64;
        ra[i] = *(const float4*)(Ap + row * KDIM + k0 + scol);
        rb[i] = *(const float4*)(Wp + row * KDIM + k0 + scol);
      }
    }
    __builtin_amdgcn_sched_barrier(0);

    // ---- phase C: compute current tile from LDS[kt&1] ----
    {
      const int buf = kt & 1;
      const int kbase = (lane >> 4) << 3;   // 8 k-elements per lane-group
      bf16x8 bf[4];
      #pragma unroll
      for (int ni = 0; ni < 4; ++ni) {
        const int rrow = wn * 64 + ni * 16 + (lane & 15);
        bf[ni] = *(const bf16x8*)&Bs[buf][rrow][swz(rrow, kbase)];
      }
      #pragma unroll
      for (int mi = 0; mi < 8; ++mi) {
        const int arow = wm * 128 + mi * 16 + (lane & 15);
        const bf16x8 af = *(const bf16x8*)&As[buf][arow][swz(arow, kbase)];
        #pragma unroll
        for (int ni = 0; ni < 4; ++ni)
          acc[mi][ni] = __builtin_amdgcn_mfma_f32_16x16x32_bf16(af, bf[ni], acc[mi][ni], 0, 0, 0);
      }
    }
  }

  // ---- epilogue: C/D layout row = (lane>>4)*4 + reg, col = lane&15 ----
  #pragma unroll
  for (int mi = 0; mi < 8; ++mi) {
    #pragma unroll
    for (int reg = 0; reg < 4; ++reg) {
      const int r = wm * 128 + mi * 16 + ((lane >> 4) << 2) + reg;
      float* rowp = C + (mBase + r) * 512 + nBase + wn * 64 + (lane & 15);
      #pragma unroll
      for (int ni = 0; ni < 4; ++ni)
        __builtin_nontemporal_store(acc[mi][ni][reg], rowp + ni * 16);
    }
  }
}

extern "C" void kernel_launch(void* const* d_in, const int* in_sizes, int n_in,
                              void* d_out, int out_size, void* d_ws, size_t ws_size,
                              hipStream_t stream) {
  const float* inputs = (const float*)d_in[0];   // [262144, 512] fp32
  const float* weight = (const float*)d_in[1];   // [8, 512, 512] fp32
  float* out = (float*)d_out;                    // [262144, 512] fp32
  (void)d_ws; (void)ws_size; (void)in_sizes; (void)n_in;

  moe_grouped_gemm<<<2048, 512, 0, stream>>>(inputs, weight, out);
}